// Round 1
// baseline (574.291 us; speedup 1.0000x reference)
//
#include <hip/hip_runtime.h>
#include <hip/hip_bf16.h>
#include <math.h>

// GCN 2-hop propagation + linear(64->2) + log_softmax, N=100000, E=1600000, D=64.
// Strategy: build CSR grouped by TARGET node on-device each launch (histogram ->
// scan -> fill), then pull-based propagation: one 64-lane wave per node, lane =
// feature dim. Hop 2 fuses the classifier + log_softmax via wave reduction.

#define NODES 100000
#define EDGES 1600000
#define DIM 64
#define NCLS 2

#define SCAN_T 256
#define SCAN_E 8
#define SCAN_CHUNK (SCAN_T * SCAN_E)  // 2048

// ---------------------------------------------------------------------------
// edge_index dtype is ambiguous (reference says int64; harness convention is
// int32). Detect on device: for int64 little-endian data, the odd 32-bit words
// of the first 64 values are all zero; for random int32 in [0,100000) the
// probability of that is ~1e-320.
__global__ void detect_dtype_kernel(const void* ei, int* mode) {
  int t = threadIdx.x;  // 0..63
  const int* p = (const int*)ei;
  int odd = p[2 * t + 1];
  unsigned long long ball = __ballot(odd == 0);
  if (t == 0) *mode = (ball == ~0ULL) ? 1 : 0;
}

__device__ __forceinline__ int edge_at(const void* ei, int mode, int idx) {
  return mode ? (int)((const long long*)ei)[idx] : ((const int*)ei)[idx];
}

// ---------------------------------------------------------------------------
__global__ void zero_int(int* p, int n) {
  int i = blockIdx.x * blockDim.x + threadIdx.x;
  if (i < n) p[i] = 0;
}

// in-degree histogram over target (col) indices
__global__ void hist_kernel(const void* ei, const int* mode, int* cnt) {
  int e = blockIdx.x * blockDim.x + threadIdx.x;
  if (e < EDGES) {
    int c = edge_at(ei, *mode, EDGES + e);
    atomicAdd(&cnt[c], 1);
  }
}

// --- 3-kernel exclusive scan of cnt[] -> row_ptr[] -------------------------
__global__ void scan_partials(const int* cnt, int* blockSums) {
  __shared__ int lds[SCAN_T];
  int b = blockIdx.x, t = threadIdx.x;
  int base = b * SCAN_CHUNK + t * SCAN_E;
  int s = 0;
#pragma unroll
  for (int k = 0; k < SCAN_E; k++) {
    int idx = base + k;
    if (idx < NODES) s += cnt[idx];
  }
  lds[t] = s;
  __syncthreads();
  for (int off = 1; off < SCAN_T; off <<= 1) {
    int v = (t >= off) ? lds[t - off] : 0;
    __syncthreads();
    lds[t] += v;
    __syncthreads();
  }
  if (t == SCAN_T - 1) blockSums[b] = lds[t];
}

__global__ void scan_offsets(int* blockSums, int nb, int* row_ptr) {
  if (threadIdx.x == 0) {
    int run = 0;
    for (int i = 0; i < nb; i++) {
      int v = blockSums[i];
      blockSums[i] = run;
      run += v;
    }
    row_ptr[NODES] = run;  // == EDGES
  }
}

__global__ void scan_final(const int* cnt, const int* blockSums, int* row_ptr,
                           int* cursor) {
  __shared__ int lds[SCAN_T];
  int b = blockIdx.x, t = threadIdx.x;
  int base = b * SCAN_CHUNK + t * SCAN_E;
  int s = 0;
#pragma unroll
  for (int k = 0; k < SCAN_E; k++) {
    int idx = base + k;
    if (idx < NODES) s += cnt[idx];
  }
  lds[t] = s;
  __syncthreads();
  for (int off = 1; off < SCAN_T; off <<= 1) {
    int v = (t >= off) ? lds[t - off] : 0;
    __syncthreads();
    lds[t] += v;
    __syncthreads();
  }
  int run = blockSums[b] + lds[t] - s;  // exclusive base for this thread
#pragma unroll
  for (int k = 0; k < SCAN_E; k++) {
    int idx = base + k;
    if (idx < NODES) {
      row_ptr[idx] = run;
      cursor[idx] = run;
      run += cnt[idx];
    }
  }
}

// dinv = rsqrt(in_degree + 1)   (self loop included; always > 0)
__global__ void dinv_kernel(const int* cnt, float* dinv) {
  int i = blockIdx.x * blockDim.x + threadIdx.x;
  if (i < NODES) dinv[i] = rsqrtf((float)(cnt[i] + 1));
}

// scatter edges into CSR buckets by target
__global__ void fill_kernel(const void* ei, const int* mode, int* cursor,
                            int* csr_src) {
  int e = blockIdx.x * blockDim.x + threadIdx.x;
  if (e < EDGES) {
    int m = *mode;
    int s = edge_at(ei, m, e);
    int c = edge_at(ei, m, EDGES + e);
    int pos = atomicAdd(&cursor[c], 1);
    csr_src[pos] = s;
  }
}

// ---------------------------------------------------------------------------
// Pull propagation: wave per node, lane = feature dim.
// y[i] = dinv[i] * ( dinv[i]*x[i] + sum_{src->i} dinv[src]*x[src] )
__global__ void prop_kernel(const float* __restrict__ xin,
                            const float* __restrict__ dinv,
                            const int* __restrict__ row_ptr,
                            const int* __restrict__ csr_src,
                            float* __restrict__ yout) {
  int wid = (blockIdx.x * (blockDim.x >> 6)) + (threadIdx.x >> 6);
  int d = threadIdx.x & 63;
  if (wid >= NODES) return;
  float di = dinv[wid];
  float acc = di * xin[(size_t)wid * DIM + d];
  int beg = row_ptr[wid];
  int end = row_ptr[wid + 1];
  for (int e = beg; e < end; ++e) {
    int s = csr_src[e];
    acc = fmaf(dinv[s], xin[(size_t)s * DIM + d], acc);
  }
  yout[(size_t)wid * DIM + d] = di * acc;
}

// Hop 2 fused with classifier: logits = y @ W^T + b, then log_softmax.
__global__ void prop_cls_kernel(const float* __restrict__ yin,
                                const float* __restrict__ dinv,
                                const int* __restrict__ row_ptr,
                                const int* __restrict__ csr_src,
                                const float* __restrict__ W,
                                const float* __restrict__ bias,
                                float* __restrict__ out) {
  int wid = (blockIdx.x * (blockDim.x >> 6)) + (threadIdx.x >> 6);
  int d = threadIdx.x & 63;
  if (wid >= NODES) return;
  float di = dinv[wid];
  float acc = di * yin[(size_t)wid * DIM + d];
  int beg = row_ptr[wid];
  int end = row_ptr[wid + 1];
  for (int e = beg; e < end; ++e) {
    int s = csr_src[e];
    acc = fmaf(dinv[s], yin[(size_t)s * DIM + d], acc);
  }
  float yv = di * acc;
  float p0 = yv * W[d];
  float p1 = yv * W[DIM + d];
#pragma unroll
  for (int off = 32; off >= 1; off >>= 1) {
    p0 += __shfl_xor(p0, off, 64);
    p1 += __shfl_xor(p1, off, 64);
  }
  if (d == 0) {
    float l0 = p0 + bias[0];
    float l1 = p1 + bias[1];
    float m = fmaxf(l0, l1);
    float ls = m + logf(expf(l0 - m) + expf(l1 - m));
    float2 o;
    o.x = l0 - ls;
    o.y = l1 - ls;
    ((float2*)out)[wid] = o;
  }
}

// ---------------------------------------------------------------------------
extern "C" void kernel_launch(void* const* d_in, const int* in_sizes, int n_in,
                              void* d_out, int out_size, void* d_ws,
                              size_t ws_size, hipStream_t stream) {
  const float* x = (const float*)d_in[0];
  const void* ei = d_in[1];
  const float* W = (const float*)d_in[2];
  const float* b = (const float*)d_in[3];
  float* out = (float*)d_out;

  char* w = (char*)d_ws;
  size_t off = 0;
  auto alloc = [&](size_t bytes) -> char* {
    char* p = w + off;
    off += (bytes + 255) & ~(size_t)255;
    return p;
  };
  int* mode = (int*)alloc(sizeof(int));
  int* cnt = (int*)alloc(NODES * sizeof(int));
  int* row_ptr = (int*)alloc((NODES + 1) * sizeof(int));
  int* cursor = (int*)alloc(NODES * sizeof(int));
  float* dinv = (float*)alloc(NODES * sizeof(float));
  int* bsums = (int*)alloc(1024 * sizeof(int));
  int* csr_src = (int*)alloc((size_t)EDGES * sizeof(int));
  float* y1 = (float*)alloc((size_t)NODES * DIM * sizeof(float));
  (void)ws_size;

  const int NB = (NODES + SCAN_CHUNK - 1) / SCAN_CHUNK;  // 49

  detect_dtype_kernel<<<1, 64, 0, stream>>>(ei, mode);
  zero_int<<<(NODES + 255) / 256, 256, 0, stream>>>(cnt, NODES);
  hist_kernel<<<(EDGES + 255) / 256, 256, 0, stream>>>(ei, mode, cnt);
  scan_partials<<<NB, SCAN_T, 0, stream>>>(cnt, bsums);
  scan_offsets<<<1, 64, 0, stream>>>(bsums, NB, row_ptr);
  scan_final<<<NB, SCAN_T, 0, stream>>>(cnt, bsums, row_ptr, cursor);
  dinv_kernel<<<(NODES + 255) / 256, 256, 0, stream>>>(cnt, dinv);
  fill_kernel<<<(EDGES + 255) / 256, 256, 0, stream>>>(ei, mode, cursor,
                                                       csr_src);

  const int WPB = 256 / 64;  // 4 nodes (waves) per block
  const int PB = (NODES + WPB - 1) / WPB;
  prop_kernel<<<PB, 256, 0, stream>>>(x, dinv, row_ptr, csr_src, y1);
  prop_cls_kernel<<<PB, 256, 0, stream>>>(y1, dinv, row_ptr, csr_src, W, b,
                                          out);
}

// Round 2
// 497.858 us; speedup vs baseline: 1.1535x; 1.1535x over previous
//
#include <hip/hip_runtime.h>
#include <hip/hip_bf16.h>
#include <math.h>

// GCN 2-hop + linear(64->2) + log_softmax. Key identity: propagation (node dim)
// commutes with the linear head (feature dim): A^2 x W^T == A^2 (x W^T).
// Project to C=2 first -> per-edge traffic is 8B, features are L2-resident
// (800KB), and accumulation is 2 float atomics/edge (push-based, no CSR).
//
// Norm folding (PyG gcn_norm, self-loops):
//   ts[i]   = dinv[i] * (x[i] @ W^T)                  (dinv = rsqrt(indeg+1))
//   acc1[i] = ts[i] + sum_{e: col=i} ts[row_e]        (hop-1 pull sum)
//   z[i]    = dinv[i]^2 * acc1[i]
//   acc2[i] = z[i] + sum_{e: col=i} z[row_e]          (hop-2)
//   logits  = dinv[i] * acc2[i] + b ; out = log_softmax(logits)

#define NODES 100000
#define EDGES 1600000
#define DIM 64

// ---------------------------------------------------------------------------
// edge_index dtype detection (int64 reference vs int32 harness convention):
// for little-endian int64, odd 32-bit words of the first 64 values are all 0;
// for random int32 in [0,100000) that has probability ~1e-320.
__global__ void detect_dtype_kernel(const void* ei, int* mode) {
  int t = threadIdx.x;  // 0..63
  const int* p = (const int*)ei;
  int odd = p[2 * t + 1];
  unsigned long long ball = __ballot(odd == 0);
  if (t == 0) *mode = (ball == ~0ULL) ? 1 : 0;
}

__global__ void zero_int(int* p, int n) {
  int i = blockIdx.x * blockDim.x + threadIdx.x;
  if (i < n) p[i] = 0;
}

// in-degree histogram over targets (col = edge_index[1]); 2 edges/thread.
__global__ void hist_kernel(const void* ei, const int* __restrict__ mode,
                            int* __restrict__ cnt) {
  int t = blockIdx.x * blockDim.x + threadIdx.x;
  int e = 2 * t;
  if (e >= EDGES) return;
  if (*mode) {
    const long long* p = (const long long*)ei + EDGES;  // col half
    longlong2 v = ((const longlong2*)(p))[t];
    atomicAdd(&cnt[(int)v.x], 1);
    atomicAdd(&cnt[(int)v.y], 1);
  } else {
    const int* p = (const int*)ei + EDGES;
    int2 v = ((const int2*)(p))[t];
    atomicAdd(&cnt[v.x], 1);
    atomicAdd(&cnt[v.y], 1);
  }
}

__global__ void dinv_kernel(const int* __restrict__ cnt,
                            float* __restrict__ dinv) {
  int i = blockIdx.x * blockDim.x + threadIdx.x;
  if (i < NODES) dinv[i] = rsqrtf((float)(cnt[i] + 1));
}

// ---------------------------------------------------------------------------
// Projection: wave per node, lane = feature. ts[i] = dinv[i]*(x[i] @ W^T).
// Also seeds acc1 = ts (self-loop term of hop 1).
__global__ void proj_kernel(const float* __restrict__ x,
                            const float* __restrict__ W,
                            const float* __restrict__ dinv,
                            float2* __restrict__ ts, float2* __restrict__ acc1) {
  int wid = (blockIdx.x * (blockDim.x >> 6)) + (threadIdx.x >> 6);
  int d = threadIdx.x & 63;
  if (wid >= NODES) return;
  float xv = x[(size_t)wid * DIM + d];
  float p0 = xv * W[d];
  float p1 = xv * W[DIM + d];
#pragma unroll
  for (int off = 32; off >= 1; off >>= 1) {
    p0 += __shfl_xor(p0, off, 64);
    p1 += __shfl_xor(p1, off, 64);
  }
  if (d == 0) {
    float di = dinv[wid];
    float2 t;
    t.x = di * p0;
    t.y = di * p1;
    ts[wid] = t;
    acc1[wid] = t;
  }
}

// Push-scatter one hop: acc[col] += src_feat[row]; 2 edges per thread.
__global__ void edge_push_kernel(const void* ei, const int* __restrict__ mode,
                                 const float2* __restrict__ feat,
                                 float* __restrict__ acc) {
  int t = blockIdx.x * blockDim.x + threadIdx.x;
  int e = 2 * t;
  if (e >= EDGES) return;
  int r0, r1, c0, c1;
  if (*mode) {
    const long long* pr = (const long long*)ei;
    longlong2 rv = ((const longlong2*)pr)[t];
    longlong2 cv = ((const longlong2*)(pr + EDGES))[t];
    r0 = (int)rv.x; r1 = (int)rv.y;
    c0 = (int)cv.x; c1 = (int)cv.y;
  } else {
    const int* pr = (const int*)ei;
    int2 rv = ((const int2*)pr)[t];
    int2 cv = ((const int2*)(pr + EDGES))[t];
    r0 = rv.x; r1 = rv.y;
    c0 = cv.x; c1 = cv.y;
  }
  float2 v0 = feat[r0];
  float2 v1 = feat[r1];
  atomicAdd(&acc[2 * c0], v0.x);
  atomicAdd(&acc[2 * c0 + 1], v0.y);
  atomicAdd(&acc[2 * c1], v1.x);
  atomicAdd(&acc[2 * c1 + 1], v1.y);
}

// z[i] = dinv[i]^2 * acc1[i]; seeds acc2 = z (self-loop term of hop 2).
__global__ void rescale_kernel(const float2* __restrict__ acc1,
                               const float* __restrict__ dinv,
                               float2* __restrict__ z,
                               float2* __restrict__ acc2) {
  int i = blockIdx.x * blockDim.x + threadIdx.x;
  if (i >= NODES) return;
  float di = dinv[i];
  float s = di * di;
  float2 a = acc1[i];
  float2 zz;
  zz.x = s * a.x;
  zz.y = s * a.y;
  z[i] = zz;
  acc2[i] = zz;
}

// logits = dinv*acc2 + b; out = log_softmax(logits).
__global__ void final_kernel(const float2* __restrict__ acc2,
                             const float* __restrict__ dinv,
                             const float* __restrict__ bias,
                             float2* __restrict__ out) {
  int i = blockIdx.x * blockDim.x + threadIdx.x;
  if (i >= NODES) return;
  float di = dinv[i];
  float2 a = acc2[i];
  float l0 = di * a.x + bias[0];
  float l1 = di * a.y + bias[1];
  float m = fmaxf(l0, l1);
  float ls = m + logf(expf(l0 - m) + expf(l1 - m));
  float2 o;
  o.x = l0 - ls;
  o.y = l1 - ls;
  out[i] = o;
}

// ---------------------------------------------------------------------------
extern "C" void kernel_launch(void* const* d_in, const int* in_sizes, int n_in,
                              void* d_out, int out_size, void* d_ws,
                              size_t ws_size, hipStream_t stream) {
  const float* x = (const float*)d_in[0];
  const void* ei = d_in[1];
  const float* W = (const float*)d_in[2];
  const float* b = (const float*)d_in[3];
  float2* out = (float2*)d_out;

  char* w = (char*)d_ws;
  size_t off = 0;
  auto alloc = [&](size_t bytes) -> char* {
    char* p = w + off;
    off += (bytes + 255) & ~(size_t)255;
    return p;
  };
  int* mode = (int*)alloc(sizeof(int));
  int* cnt = (int*)alloc(NODES * sizeof(int));
  float* dinv = (float*)alloc(NODES * sizeof(float));
  float2* ts = (float2*)alloc(NODES * sizeof(float2));
  float2* acc1 = (float2*)alloc(NODES * sizeof(float2));
  float2* z = (float2*)alloc(NODES * sizeof(float2));
  float2* acc2 = (float2*)alloc(NODES * sizeof(float2));
  (void)ws_size;

  detect_dtype_kernel<<<1, 64, 0, stream>>>(ei, mode);
  zero_int<<<(NODES + 255) / 256, 256, 0, stream>>>(cnt, NODES);
  hist_kernel<<<(EDGES / 2 + 255) / 256, 256, 0, stream>>>(ei, mode, cnt);
  dinv_kernel<<<(NODES + 255) / 256, 256, 0, stream>>>(cnt, dinv);

  const int WPB = 256 / 64;  // 4 waves (nodes) per block
  proj_kernel<<<(NODES + WPB - 1) / WPB, 256, 0, stream>>>(x, W, dinv, ts,
                                                           acc1);
  edge_push_kernel<<<(EDGES / 2 + 255) / 256, 256, 0, stream>>>(
      ei, mode, ts, (float*)acc1);
  rescale_kernel<<<(NODES + 255) / 256, 256, 0, stream>>>(acc1, dinv, z, acc2);
  edge_push_kernel<<<(EDGES / 2 + 255) / 256, 256, 0, stream>>>(
      ei, mode, z, (float*)acc2);
  final_kernel<<<(NODES + 255) / 256, 256, 0, stream>>>(acc2, dinv, b, out);
}

// Round 3
// 331.401 us; speedup vs baseline: 1.7329x; 1.5023x over previous
//
#include <hip/hip_runtime.h>
#include <hip/hip_bf16.h>
#include <math.h>

// GCN 2-hop + linear(64->2) + log_softmax, N=100000, E=1600000, D=64.
//
// Identity: propagation commutes with the linear head: A^2 x W^T == A^2 (xW^T).
// Project to C=2 first (ts = dinv * xW^T), then 2 pull-based hops over a CSR
// (grouped by target) built on-device. Pull = deterministic gathers from an
// 800KB L2-resident feature array; NO float atomics (round-2 rocprof showed
// fp32 global atomics are memory-side on MI355X: 16B HBM write + serialized
// RMW per op -> 169us/hop). CSR build uses int atomics only (2x fewer ops
// than one push hop, paid once).
//
// Norm folding (PyG gcn_norm with self-loops, dinv = rsqrt(indeg+1)):
//   ts[i] = dinv[i] * (x[i] @ W^T)
//   z[i]  = dinv[i]^2 * (ts[i] + sum_{e:col=i} ts[row_e])      (hop 1)
//   l[i]  = dinv[i]   * (z[i]  + sum_{e:col=i} z[row_e]) + b   (hop 2)
//   out   = log_softmax(l)

#define NODES 100000
#define EDGES 1600000
#define DIM 64

#define SCAN_T 256
#define SCAN_E 8
#define SCAN_CHUNK (SCAN_T * SCAN_E)  // 2048

// ---------------------------------------------------------------------------
// edge_index dtype detection (int64 reference vs int32 harness convention):
// little-endian int64 -> odd 32-bit words of first 64 values all zero.
__global__ void detect_dtype_kernel(const void* ei, int* mode) {
  int t = threadIdx.x;  // 0..63
  const int* p = (const int*)ei;
  int odd = p[2 * t + 1];
  unsigned long long ball = __ballot(odd == 0);
  if (t == 0) *mode = (ball == ~0ULL) ? 1 : 0;
}

__global__ void zero_int(int* p, int n) {
  int i = blockIdx.x * blockDim.x + threadIdx.x;
  if (i < n) p[i] = 0;
}

// in-degree histogram over targets (col = edge_index[1]); 2 edges/thread.
__global__ void hist_kernel(const void* ei, const int* __restrict__ mode,
                            int* __restrict__ cnt) {
  int t = blockIdx.x * blockDim.x + threadIdx.x;
  if (2 * t >= EDGES) return;
  if (*mode) {
    const long long* p = (const long long*)ei + EDGES;  // col half
    longlong2 v = ((const longlong2*)(p))[t];
    atomicAdd(&cnt[(int)v.x], 1);
    atomicAdd(&cnt[(int)v.y], 1);
  } else {
    const int* p = (const int*)ei + EDGES;
    int2 v = ((const int2*)(p))[t];
    atomicAdd(&cnt[v.x], 1);
    atomicAdd(&cnt[v.y], 1);
  }
}

// --- 3-kernel exclusive scan of cnt[] -> row_ptr[] / cursor[] --------------
__global__ void scan_partials(const int* __restrict__ cnt,
                              int* __restrict__ blockSums) {
  __shared__ int lds[SCAN_T];
  int b = blockIdx.x, t = threadIdx.x;
  int base = b * SCAN_CHUNK + t * SCAN_E;
  int s = 0;
#pragma unroll
  for (int k = 0; k < SCAN_E; k++) {
    int idx = base + k;
    if (idx < NODES) s += cnt[idx];
  }
  lds[t] = s;
  __syncthreads();
  for (int off = 1; off < SCAN_T; off <<= 1) {
    int v = (t >= off) ? lds[t - off] : 0;
    __syncthreads();
    lds[t] += v;
    __syncthreads();
  }
  if (t == SCAN_T - 1) blockSums[b] = lds[t];
}

__global__ void scan_offsets(int* blockSums, int nb, int* row_ptr) {
  if (threadIdx.x == 0) {
    int run = 0;
    for (int i = 0; i < nb; i++) {
      int v = blockSums[i];
      blockSums[i] = run;
      run += v;
    }
    row_ptr[NODES] = run;  // == EDGES
  }
}

// final scan pass; also emits cursor copy and dinv = rsqrt(cnt+1).
__global__ void scan_final(const int* __restrict__ cnt,
                           const int* __restrict__ blockSums,
                           int* __restrict__ row_ptr, int* __restrict__ cursor,
                           float* __restrict__ dinv) {
  __shared__ int lds[SCAN_T];
  int b = blockIdx.x, t = threadIdx.x;
  int base = b * SCAN_CHUNK + t * SCAN_E;
  int s = 0;
#pragma unroll
  for (int k = 0; k < SCAN_E; k++) {
    int idx = base + k;
    if (idx < NODES) s += cnt[idx];
  }
  lds[t] = s;
  __syncthreads();
  for (int off = 1; off < SCAN_T; off <<= 1) {
    int v = (t >= off) ? lds[t - off] : 0;
    __syncthreads();
    lds[t] += v;
    __syncthreads();
  }
  int run = blockSums[b] + lds[t] - s;  // exclusive base for this thread
#pragma unroll
  for (int k = 0; k < SCAN_E; k++) {
    int idx = base + k;
    if (idx < NODES) {
      int c = cnt[idx];
      row_ptr[idx] = run;
      cursor[idx] = run;
      dinv[idx] = rsqrtf((float)(c + 1));
      run += c;
    }
  }
}

// scatter edges into CSR buckets by target; 2 edges/thread.
__global__ void fill_kernel(const void* ei, const int* __restrict__ mode,
                            int* __restrict__ cursor, int* __restrict__ csr_src) {
  int t = blockIdx.x * blockDim.x + threadIdx.x;
  if (2 * t >= EDGES) return;
  int r0, r1, c0, c1;
  if (*mode) {
    const long long* pr = (const long long*)ei;
    longlong2 rv = ((const longlong2*)pr)[t];
    longlong2 cv = ((const longlong2*)(pr + EDGES))[t];
    r0 = (int)rv.x; r1 = (int)rv.y;
    c0 = (int)cv.x; c1 = (int)cv.y;
  } else {
    const int* pr = (const int*)ei;
    int2 rv = ((const int2*)pr)[t];
    int2 cv = ((const int2*)(pr + EDGES))[t];
    r0 = rv.x; r1 = rv.y;
    c0 = cv.x; c1 = cv.y;
  }
  int p0 = atomicAdd(&cursor[c0], 1);
  csr_src[p0] = r0;
  int p1 = atomicAdd(&cursor[c1], 1);
  csr_src[p1] = r1;
}

// ---------------------------------------------------------------------------
// Projection: wave per node, lane = feature. ts[i] = dinv[i]*(x[i] @ W^T).
__global__ void proj_kernel(const float* __restrict__ x,
                            const float* __restrict__ W,
                            const float* __restrict__ dinv,
                            float2* __restrict__ ts) {
  int wid = (blockIdx.x * (blockDim.x >> 6)) + (threadIdx.x >> 6);
  int d = threadIdx.x & 63;
  if (wid >= NODES) return;
  float xv = x[(size_t)wid * DIM + d];
  float p0 = xv * W[d];
  float p1 = xv * W[DIM + d];
#pragma unroll
  for (int off = 32; off >= 1; off >>= 1) {
    p0 += __shfl_xor(p0, off, 64);
    p1 += __shfl_xor(p1, off, 64);
  }
  if (d == 0) {
    float di = dinv[wid];
    float2 t;
    t.x = di * p0;
    t.y = di * p1;
    ts[wid] = t;
  }
}

// Hop 1 pull: 32 lanes per node, lane = edge slot (parallel gathers, shuffle
// reduce). z[i] = dinv[i]^2 * (ts[i] + sum ts[src]).
__global__ void hop1_kernel(const float2* __restrict__ ts,
                            const float* __restrict__ dinv,
                            const int* __restrict__ row_ptr,
                            const int* __restrict__ csr_src,
                            float2* __restrict__ z) {
  int g = (blockIdx.x * (blockDim.x >> 5)) + (threadIdx.x >> 5);
  int lane = threadIdx.x & 31;
  if (g >= NODES) return;
  int beg = row_ptr[g];
  int end = row_ptr[g + 1];
  float ax = 0.f, ay = 0.f;
  for (int e = beg + lane; e < end; e += 32) {
    float2 v = ts[csr_src[e]];
    ax += v.x;
    ay += v.y;
  }
#pragma unroll
  for (int off = 16; off >= 1; off >>= 1) {
    ax += __shfl_xor(ax, off, 64);
    ay += __shfl_xor(ay, off, 64);
  }
  if (lane == 0) {
    float di = dinv[g];
    float s = di * di;
    float2 t0 = ts[g];
    float2 o;
    o.x = s * (ax + t0.x);
    o.y = s * (ay + t0.y);
    z[g] = o;
  }
}

// Hop 2 pull fused with bias + log_softmax.
__global__ void hop2_kernel(const float2* __restrict__ z,
                            const float* __restrict__ dinv,
                            const int* __restrict__ row_ptr,
                            const int* __restrict__ csr_src,
                            const float* __restrict__ bias,
                            float2* __restrict__ out) {
  int g = (blockIdx.x * (blockDim.x >> 5)) + (threadIdx.x >> 5);
  int lane = threadIdx.x & 31;
  if (g >= NODES) return;
  int beg = row_ptr[g];
  int end = row_ptr[g + 1];
  float ax = 0.f, ay = 0.f;
  for (int e = beg + lane; e < end; e += 32) {
    float2 v = z[csr_src[e]];
    ax += v.x;
    ay += v.y;
  }
#pragma unroll
  for (int off = 16; off >= 1; off >>= 1) {
    ax += __shfl_xor(ax, off, 64);
    ay += __shfl_xor(ay, off, 64);
  }
  if (lane == 0) {
    float di = dinv[g];
    float2 z0 = z[g];
    float l0 = di * (ax + z0.x) + bias[0];
    float l1 = di * (ay + z0.y) + bias[1];
    float m = fmaxf(l0, l1);
    float ls = m + logf(expf(l0 - m) + expf(l1 - m));
    float2 o;
    o.x = l0 - ls;
    o.y = l1 - ls;
    out[g] = o;
  }
}

// ---------------------------------------------------------------------------
extern "C" void kernel_launch(void* const* d_in, const int* in_sizes, int n_in,
                              void* d_out, int out_size, void* d_ws,
                              size_t ws_size, hipStream_t stream) {
  const float* x = (const float*)d_in[0];
  const void* ei = d_in[1];
  const float* W = (const float*)d_in[2];
  const float* b = (const float*)d_in[3];
  float2* out = (float2*)d_out;

  char* w = (char*)d_ws;
  size_t off = 0;
  auto alloc = [&](size_t bytes) -> char* {
    char* p = w + off;
    off += (bytes + 255) & ~(size_t)255;
    return p;
  };
  int* mode = (int*)alloc(sizeof(int));
  int* cnt = (int*)alloc(NODES * sizeof(int));
  int* row_ptr = (int*)alloc((NODES + 1) * sizeof(int));
  int* cursor = (int*)alloc(NODES * sizeof(int));
  float* dinv = (float*)alloc(NODES * sizeof(float));
  int* bsums = (int*)alloc(1024 * sizeof(int));
  int* csr_src = (int*)alloc((size_t)EDGES * sizeof(int));
  float2* ts = (float2*)alloc(NODES * sizeof(float2));
  float2* z = (float2*)alloc(NODES * sizeof(float2));
  (void)ws_size;

  const int NB = (NODES + SCAN_CHUNK - 1) / SCAN_CHUNK;  // 49

  detect_dtype_kernel<<<1, 64, 0, stream>>>(ei, mode);
  zero_int<<<(NODES + 255) / 256, 256, 0, stream>>>(cnt, NODES);
  hist_kernel<<<(EDGES / 2 + 255) / 256, 256, 0, stream>>>(ei, mode, cnt);
  scan_partials<<<NB, SCAN_T, 0, stream>>>(cnt, bsums);
  scan_offsets<<<1, 64, 0, stream>>>(bsums, NB, row_ptr);
  scan_final<<<NB, SCAN_T, 0, stream>>>(cnt, bsums, row_ptr, cursor, dinv);
  fill_kernel<<<(EDGES / 2 + 255) / 256, 256, 0, stream>>>(ei, mode, cursor,
                                                           csr_src);

  const int WPB = 256 / 64;  // waves per block (proj)
  proj_kernel<<<(NODES + WPB - 1) / WPB, 256, 0, stream>>>(x, W, dinv, ts);

  const int GPB = 256 / 32;  // 8 nodes per block (hops)
  hop1_kernel<<<(NODES + GPB - 1) / GPB, 256, 0, stream>>>(ts, dinv, row_ptr,
                                                           csr_src, z);
  hop2_kernel<<<(NODES + GPB - 1) / GPB, 256, 0, stream>>>(z, dinv, row_ptr,
                                                           csr_src, b, out);
}

// Round 4
// 178.400 us; speedup vs baseline: 3.2191x; 1.8576x over previous
//
#include <hip/hip_runtime.h>
#include <hip/hip_bf16.h>
#include <math.h>

// GCN 2-hop + linear(64->2) + log_softmax, N=100000, E=1600000, D=64.
//
// Pipeline (no node-granular global scatters anywhere — R2/R3 rocprof showed
// those cost ~100us/pass in HBM write amplification):
//   1. radix-partition edges into P=25 target-range buckets (4096 nodes each)
//      with per-(block,bucket) contiguous chunks -> coalesced full-line writes.
//   2. degree = bucketed LDS int histogram + slice merge -> dinv=rsqrt(deg+1)
//   3. ts = dinv * (x @ W^T)    (projection commutes with propagation; C=2)
//   4. hop = bucketed LDS float2 segment-sum of ts -> partials -> merge
//      z = dinv^2*(ts + sum)  (hop1);  logits = dinv*(z + sum)+b (hop2)
//   5. out = log_softmax(logits), fused into hop-2 merge.

#define NODES 100000
#define EDGES 1600000
#define DIM 64

#define PBITS 12
#define PSIZE 4096                 // nodes per bucket
#define P_BUCKETS 25               // ceil(100000/4096)
#define CAP 160000                 // edge capacity per bucket (2.44x mean)
#define NSLICE 10                  // slices per bucket in deg/hop passes
#define PART_BLOCKS 256            // partition kernel blocks
#define SEG (EDGES / PART_BLOCKS)  // 6250 edges per partition block

// ---------------------------------------------------------------------------
// Detect edge_index dtype (int64 vs int32) + init bucket cursors.
// little-endian int64 -> odd 32-bit words of first 64 values all zero.
__global__ void detect_init_kernel(const void* ei, int* mode, int* cursor) {
  int t = threadIdx.x;  // 0..63
  const int* p = (const int*)ei;
  unsigned long long ball = __ballot(p[2 * t + 1] == 0);
  if (t == 0) *mode = (ball == ~0ULL) ? 1 : 0;
  if (t < P_BUCKETS) cursor[t] = t * CAP;
}

// ---------------------------------------------------------------------------
// Radix partition by target bucket. Each block owns a contiguous segment of
// SEG edges. Pass 1: LDS-count buckets. Reserve per-bucket chunks (25 global
// atomics/block). Pass 2: re-read edges, rank via LDS atomics, write (r,c)
// int32 SoA contiguously into the block's chunks.
__global__ void partition_kernel(const void* ei, const int* __restrict__ mode,
                                 int* __restrict__ cursor,
                                 int* __restrict__ rbuf,
                                 int* __restrict__ cbuf) {
  __shared__ int lcnt[P_BUCKETS];
  __shared__ int lbase[P_BUCKETS];
  int t = threadIdx.x;
  int m = *mode;
  int beg = blockIdx.x * SEG;
  int end = beg + SEG;

  if (t < P_BUCKETS) lcnt[t] = 0;
  __syncthreads();

  // pass 1: count (targets only)
  for (int e = beg + t; e < end; e += 256) {
    int c = m ? (int)((const long long*)ei)[EDGES + e]
              : ((const int*)ei)[EDGES + e];
    atomicAdd(&lcnt[c >> PBITS], 1);
  }
  __syncthreads();
  if (t < P_BUCKETS) {
    lbase[t] = atomicAdd(&cursor[t], lcnt[t]);
    lcnt[t] = 0;  // reuse as local rank cursor
  }
  __syncthreads();

  // pass 2: scatter into block-private contiguous chunks
  for (int e = beg + t; e < end; e += 256) {
    int r, c;
    if (m) {
      r = (int)((const long long*)ei)[e];
      c = (int)((const long long*)ei)[EDGES + e];
    } else {
      r = ((const int*)ei)[e];
      c = ((const int*)ei)[EDGES + e];
    }
    int b = c >> PBITS;
    int pos = lbase[b] + atomicAdd(&lcnt[b], 1);
    if (pos < (b + 1) * CAP) {  // safety vs bucket overflow
      rbuf[pos] = r;
      cbuf[pos] = c;
    }
  }
}

// ---------------------------------------------------------------------------
// Degree histogram: block (p,s) counts its slice of bucket p into LDS ints.
__global__ void deg_kernel(const int* __restrict__ cursor,
                           const int* __restrict__ cbuf,
                           int* __restrict__ dpart) {
  __shared__ int lds[PSIZE];
  int p = blockIdx.x / NSLICE, s = blockIdx.x % NSLICE;
  for (int i = threadIdx.x; i < PSIZE; i += 256) lds[i] = 0;
  __syncthreads();
  int base = p * CAP;
  int cnt = min(cursor[p] - base, CAP);
  int per = (cnt + NSLICE - 1) / NSLICE;
  int beg = base + s * per;
  int end = min(base + cnt, beg + per);
  for (int e = beg + threadIdx.x; e < end; e += 256)
    atomicAdd(&lds[cbuf[e] & (PSIZE - 1)], 1);
  __syncthreads();
  int* out = dpart + (size_t)blockIdx.x * PSIZE;
  for (int i = threadIdx.x; i < PSIZE; i += 256) out[i] = lds[i];
}

__global__ void dinv_merge_kernel(const int* __restrict__ dpart,
                                  float* __restrict__ dinv) {
  int i = blockIdx.x * blockDim.x + threadIdx.x;
  if (i >= NODES) return;
  int p = i >> PBITS, l = i & (PSIZE - 1);
  int d = 0;
#pragma unroll
  for (int s = 0; s < NSLICE; s++) d += dpart[(size_t)(p * NSLICE + s) * PSIZE + l];
  dinv[i] = rsqrtf((float)(d + 1));
}

// ---------------------------------------------------------------------------
// Projection: wave per node, lane = feature. ts[i] = dinv[i]*(x[i] @ W^T).
__global__ void proj_kernel(const float* __restrict__ x,
                            const float* __restrict__ W,
                            const float* __restrict__ dinv,
                            float2* __restrict__ ts) {
  int wid = (blockIdx.x * (blockDim.x >> 6)) + (threadIdx.x >> 6);
  int d = threadIdx.x & 63;
  if (wid >= NODES) return;
  float xv = x[(size_t)wid * DIM + d];
  float p0 = xv * W[d];
  float p1 = xv * W[DIM + d];
#pragma unroll
  for (int off = 32; off >= 1; off >>= 1) {
    p0 += __shfl_xor(p0, off, 64);
    p1 += __shfl_xor(p1, off, 64);
  }
  if (d == 0) {
    float di = dinv[wid];
    float2 t;
    t.x = di * p0;
    t.y = di * p1;
    ts[wid] = t;
  }
}

// ---------------------------------------------------------------------------
// One propagation hop: block (p,s) accumulates feat[src] for its slice of
// bucket p into a 4096-wide LDS float2 accumulator (ds_add_f32 atomics),
// then writes a dense partial. No global scatters.
__global__ void hop_kernel(const int* __restrict__ cursor,
                           const int* __restrict__ rbuf,
                           const int* __restrict__ cbuf,
                           const float2* __restrict__ feat,
                           float2* __restrict__ hpart) {
  __shared__ float lx[PSIZE];
  __shared__ float ly[PSIZE];
  int p = blockIdx.x / NSLICE, s = blockIdx.x % NSLICE;
  for (int i = threadIdx.x; i < PSIZE; i += 256) {
    lx[i] = 0.f;
    ly[i] = 0.f;
  }
  __syncthreads();
  int base = p * CAP;
  int cnt = min(cursor[p] - base, CAP);
  int per = (cnt + NSLICE - 1) / NSLICE;
  int beg = base + s * per;
  int end = min(base + cnt, beg + per);
  for (int e = beg + threadIdx.x; e < end; e += 256) {
    int r = rbuf[e];
    int cl = cbuf[e] & (PSIZE - 1);
    float2 v = feat[r];
    atomicAdd(&lx[cl], v.x);
    atomicAdd(&ly[cl], v.y);
  }
  __syncthreads();
  float2* out = hpart + (size_t)blockIdx.x * PSIZE;
  for (int i = threadIdx.x; i < PSIZE; i += 256) {
    float2 o;
    o.x = lx[i];
    o.y = ly[i];
    out[i] = o;
  }
}

// merge hop-1 partials: z = dinv^2 * (ts + sum_slices)
__global__ void merge1_kernel(const float2* __restrict__ hpart,
                              const float2* __restrict__ ts,
                              const float* __restrict__ dinv,
                              float2* __restrict__ z) {
  int i = blockIdx.x * blockDim.x + threadIdx.x;
  if (i >= NODES) return;
  int p = i >> PBITS, l = i & (PSIZE - 1);
  float2 t0 = ts[i];
  float ax = t0.x, ay = t0.y;
#pragma unroll
  for (int s = 0; s < NSLICE; s++) {
    float2 v = hpart[(size_t)(p * NSLICE + s) * PSIZE + l];
    ax += v.x;
    ay += v.y;
  }
  float di = dinv[i];
  float sc = di * di;
  float2 o;
  o.x = sc * ax;
  o.y = sc * ay;
  z[i] = o;
}

// merge hop-2 partials + bias + log_softmax -> out
__global__ void merge2_kernel(const float2* __restrict__ hpart,
                              const float2* __restrict__ z,
                              const float* __restrict__ dinv,
                              const float* __restrict__ bias,
                              float2* __restrict__ out) {
  int i = blockIdx.x * blockDim.x + threadIdx.x;
  if (i >= NODES) return;
  int p = i >> PBITS, l = i & (PSIZE - 1);
  float2 z0 = z[i];
  float ax = z0.x, ay = z0.y;
#pragma unroll
  for (int s = 0; s < NSLICE; s++) {
    float2 v = hpart[(size_t)(p * NSLICE + s) * PSIZE + l];
    ax += v.x;
    ay += v.y;
  }
  float di = dinv[i];
  float l0 = di * ax + bias[0];
  float l1 = di * ay + bias[1];
  float m = fmaxf(l0, l1);
  float ls = m + logf(expf(l0 - m) + expf(l1 - m));
  float2 o;
  o.x = l0 - ls;
  o.y = l1 - ls;
  out[i] = o;
}

// ---------------------------------------------------------------------------
extern "C" void kernel_launch(void* const* d_in, const int* in_sizes, int n_in,
                              void* d_out, int out_size, void* d_ws,
                              size_t ws_size, hipStream_t stream) {
  const float* x = (const float*)d_in[0];
  const void* ei = d_in[1];
  const float* W = (const float*)d_in[2];
  const float* b = (const float*)d_in[3];
  float2* out = (float2*)d_out;

  char* w = (char*)d_ws;
  size_t off = 0;
  auto alloc = [&](size_t bytes) -> char* {
    char* p = w + off;
    off += (bytes + 255) & ~(size_t)255;
    return p;
  };
  int* mode = (int*)alloc(sizeof(int));
  int* cursor = (int*)alloc(P_BUCKETS * sizeof(int));
  int* rbuf = (int*)alloc((size_t)P_BUCKETS * CAP * sizeof(int));    // 16 MB
  int* cbuf = (int*)alloc((size_t)P_BUCKETS * CAP * sizeof(int));    // 16 MB
  int* dpart = (int*)alloc((size_t)P_BUCKETS * NSLICE * PSIZE * sizeof(int));
  float* dinv = (float*)alloc(NODES * sizeof(float));
  float2* ts = (float2*)alloc(NODES * sizeof(float2));
  float2* z = (float2*)alloc(NODES * sizeof(float2));
  float2* hpart =
      (float2*)alloc((size_t)P_BUCKETS * NSLICE * PSIZE * sizeof(float2));
  (void)ws_size;

  const int NGRID = (NODES + 255) / 256;

  detect_init_kernel<<<1, 64, 0, stream>>>(ei, mode, cursor);
  partition_kernel<<<PART_BLOCKS, 256, 0, stream>>>(ei, mode, cursor, rbuf,
                                                    cbuf);
  deg_kernel<<<P_BUCKETS * NSLICE, 256, 0, stream>>>(cursor, cbuf, dpart);
  dinv_merge_kernel<<<NGRID, 256, 0, stream>>>(dpart, dinv);

  const int WPB = 256 / 64;  // 4 waves (nodes) per block
  proj_kernel<<<(NODES + WPB - 1) / WPB, 256, 0, stream>>>(x, W, dinv, ts);

  hop_kernel<<<P_BUCKETS * NSLICE, 256, 0, stream>>>(cursor, rbuf, cbuf, ts,
                                                     hpart);
  merge1_kernel<<<NGRID, 256, 0, stream>>>(hpart, ts, dinv, z);
  hop_kernel<<<P_BUCKETS * NSLICE, 256, 0, stream>>>(cursor, rbuf, cbuf, z,
                                                     hpart);
  merge2_kernel<<<NGRID, 256, 0, stream>>>(hpart, z, dinv, b, out);
}

// Round 5
// 177.406 us; speedup vs baseline: 3.2372x; 1.0056x over previous
//
#include <hip/hip_runtime.h>
#include <hip/hip_bf16.h>
#include <math.h>

// GCN 2-hop + linear(64->2) + log_softmax, N=100000, E=1600000, D=64.
//
// Pipeline (no node-granular global scatters — R2/R3 showed ~100us/pass HBM
// write amplification for those on MI355X):
//   1. radix-partition edges into P=25 target buckets (4096 nodes each),
//      per-block contiguous chunks; emit packed int2{src, col&4095}.
//   2. per-bucket LDS histogram -> dinv = rsqrt(deg+1) directly (1 blk/bucket)
//   3. ts = dinv * (x @ W^T)   (projection commutes with propagation; C=2)
//   4. hop = (bucket,slice) LDS float2 segment-sum -> dense partials -> merge
//      z = dinv^2*(ts + sum)  (hop1);  logits = dinv*(z + sum)+b  (hop2)
//   5. log_softmax fused into hop-2 merge.

#define NODES 100000
#define EDGES 1600000
#define DIM 64

#define PBITS 12
#define PSIZE 4096                 // nodes per bucket
#define P_BUCKETS 25               // ceil(100000/4096)
#define CAP 131072                 // edge capacity per bucket (2x mean)
#define NSLICE 10                  // slices per bucket in hop pass
#define PART_BLOCKS 256
#define SEG (EDGES / PART_BLOCKS)  // 6250 edges per partition block
#define PAIRS (SEG / 2)            // 3125 edge-pairs per block

// ---------------------------------------------------------------------------
// mode detect (int64 vs int32 edge_index) + bucket cursor init.
__global__ void init_kernel(const void* ei, int* mode, int* cursor) {
  int t = threadIdx.x;  // 0..63
  const int* p = (const int*)ei;
  unsigned long long ball = __ballot(p[2 * t + 1] == 0);
  if (t == 0) *mode = (ball == ~0ULL) ? 1 : 0;
  if (t < P_BUCKETS) cursor[t] = t * CAP;
}

// ---------------------------------------------------------------------------
// Radix partition by target bucket. Each block owns SEG contiguous edges.
// Pass 1: LDS bucket counts. Reserve chunks (25 global atomics/block).
// Pass 2: rank via LDS atomics, store one int2{src, col&4095} per edge.
__global__ void partition_kernel(const void* ei, const int* __restrict__ mode,
                                 int* __restrict__ cursor,
                                 int2* __restrict__ ecbuf) {
  __shared__ int lcnt[P_BUCKETS];
  __shared__ int lbase[P_BUCKETS];
  int t = threadIdx.x;
  int m = *mode;
  int pbase = blockIdx.x * PAIRS;

  if (t < P_BUCKETS) lcnt[t] = 0;
  __syncthreads();

  // pass 1: count targets
  if (m) {
    const longlong2* cp =
        (const longlong2*)((const long long*)ei + EDGES) + pbase;
    for (int i = t; i < PAIRS; i += 256) {
      longlong2 v = cp[i];
      atomicAdd(&lcnt[((int)v.x) >> PBITS], 1);
      atomicAdd(&lcnt[((int)v.y) >> PBITS], 1);
    }
  } else {
    const int2* cp = (const int2*)((const int*)ei + EDGES) + pbase;
    for (int i = t; i < PAIRS; i += 256) {
      int2 v = cp[i];
      atomicAdd(&lcnt[v.x >> PBITS], 1);
      atomicAdd(&lcnt[v.y >> PBITS], 1);
    }
  }
  __syncthreads();
  if (t < P_BUCKETS) {
    lbase[t] = atomicAdd(&cursor[t], lcnt[t]);
    lcnt[t] = 0;  // reuse as rank cursor
  }
  __syncthreads();

  // pass 2: scatter packed edges into block-private contiguous chunks
  if (m) {
    const longlong2* rp = (const longlong2*)ei + pbase;
    const longlong2* cp =
        (const longlong2*)((const long long*)ei + EDGES) + pbase;
    for (int i = t; i < PAIRS; i += 256) {
      longlong2 rv = rp[i];
      longlong2 cv = cp[i];
      int r0 = (int)rv.x, c0 = (int)cv.x;
      int b0 = c0 >> PBITS;
      int p0 = lbase[b0] + atomicAdd(&lcnt[b0], 1);
      if (p0 < (b0 + 1) * CAP) ecbuf[p0] = make_int2(r0, c0 & (PSIZE - 1));
      int r1 = (int)rv.y, c1 = (int)cv.y;
      int b1 = c1 >> PBITS;
      int p1 = lbase[b1] + atomicAdd(&lcnt[b1], 1);
      if (p1 < (b1 + 1) * CAP) ecbuf[p1] = make_int2(r1, c1 & (PSIZE - 1));
    }
  } else {
    const int2* rp = (const int2*)ei + pbase;
    const int2* cp = (const int2*)((const int*)ei + EDGES) + pbase;
    for (int i = t; i < PAIRS; i += 256) {
      int2 rv = rp[i];
      int2 cv = cp[i];
      int b0 = cv.x >> PBITS;
      int p0 = lbase[b0] + atomicAdd(&lcnt[b0], 1);
      if (p0 < (b0 + 1) * CAP) ecbuf[p0] = make_int2(rv.x, cv.x & (PSIZE - 1));
      int b1 = cv.y >> PBITS;
      int p1 = lbase[b1] + atomicAdd(&lcnt[b1], 1);
      if (p1 < (b1 + 1) * CAP) ecbuf[p1] = make_int2(rv.y, cv.y & (PSIZE - 1));
    }
  }
}

// ---------------------------------------------------------------------------
// Degree histogram + dinv, one block per bucket (1024 threads, 16KB LDS).
__global__ void deg_kernel(const int* __restrict__ cursor,
                           const int2* __restrict__ ecbuf,
                           float* __restrict__ dinv) {
  __shared__ int h[PSIZE];
  int p = blockIdx.x;
  for (int i = threadIdx.x; i < PSIZE; i += 1024) h[i] = 0;
  __syncthreads();
  int base = p * CAP;
  int cnt = min(cursor[p] - base, CAP);
  for (int e = threadIdx.x; e < cnt; e += 1024)
    atomicAdd(&h[ecbuf[base + e].y], 1);
  __syncthreads();
  int gbase = p << PBITS;
  for (int i = threadIdx.x; i < PSIZE; i += 1024) {
    int g = gbase + i;
    if (g < NODES) dinv[g] = rsqrtf((float)(h[i] + 1));
  }
}

// ---------------------------------------------------------------------------
// Projection: wave per node, lane = feature. ts[i] = dinv[i]*(x[i] @ W^T).
__global__ void proj_kernel(const float* __restrict__ x,
                            const float* __restrict__ W,
                            const float* __restrict__ dinv,
                            float2* __restrict__ ts) {
  int wid = (blockIdx.x * (blockDim.x >> 6)) + (threadIdx.x >> 6);
  int d = threadIdx.x & 63;
  if (wid >= NODES) return;
  float xv = x[(size_t)wid * DIM + d];
  float p0 = xv * W[d];
  float p1 = xv * W[DIM + d];
#pragma unroll
  for (int off = 32; off >= 1; off >>= 1) {
    p0 += __shfl_xor(p0, off, 64);
    p1 += __shfl_xor(p1, off, 64);
  }
  if (d == 0) {
    float di = dinv[wid];
    float2 t;
    t.x = di * p0;
    t.y = di * p1;
    ts[wid] = t;
  }
}

// ---------------------------------------------------------------------------
// One hop: block (p,s) LDS-accumulates feat[src] for its slice of bucket p
// (ds_add_f32), writes a dense 4096-wide partial. 512 threads for latency
// hiding of the L2-resident feat gathers.
__global__ void hop_kernel(const int* __restrict__ cursor,
                           const int2* __restrict__ ecbuf,
                           const float2* __restrict__ feat,
                           float2* __restrict__ hpart) {
  __shared__ float lx[PSIZE];
  __shared__ float ly[PSIZE];
  int p = blockIdx.x / NSLICE, s = blockIdx.x % NSLICE;
  for (int i = threadIdx.x; i < PSIZE; i += 512) {
    lx[i] = 0.f;
    ly[i] = 0.f;
  }
  __syncthreads();
  int base = p * CAP;
  int cnt = min(cursor[p] - base, CAP);
  int per = (cnt + NSLICE - 1) / NSLICE;
  int beg = base + s * per;
  int end = min(base + cnt, beg + per);
  for (int e = beg + threadIdx.x; e < end; e += 512) {
    int2 ec = ecbuf[e];
    float2 v = feat[ec.x];
    atomicAdd(&lx[ec.y], v.x);
    atomicAdd(&ly[ec.y], v.y);
  }
  __syncthreads();
  float2* outp = hpart + (size_t)blockIdx.x * PSIZE;
  for (int i = threadIdx.x; i < PSIZE; i += 512) {
    float2 o;
    o.x = lx[i];
    o.y = ly[i];
    outp[i] = o;
  }
}

// merge hop-1 partials: z = dinv^2 * (ts + sum_slices)
__global__ void merge1_kernel(const float2* __restrict__ hpart,
                              const float2* __restrict__ ts,
                              const float* __restrict__ dinv,
                              float2* __restrict__ z) {
  int i = blockIdx.x * blockDim.x + threadIdx.x;
  if (i >= NODES) return;
  int p = i >> PBITS, l = i & (PSIZE - 1);
  float2 t0 = ts[i];
  float ax = t0.x, ay = t0.y;
#pragma unroll
  for (int s = 0; s < NSLICE; s++) {
    float2 v = hpart[(size_t)(p * NSLICE + s) * PSIZE + l];
    ax += v.x;
    ay += v.y;
  }
  float di = dinv[i];
  float sc = di * di;
  float2 o;
  o.x = sc * ax;
  o.y = sc * ay;
  z[i] = o;
}

// merge hop-2 partials + bias + log_softmax -> out
__global__ void merge2_kernel(const float2* __restrict__ hpart,
                              const float2* __restrict__ z,
                              const float* __restrict__ dinv,
                              const float* __restrict__ bias,
                              float2* __restrict__ out) {
  int i = blockIdx.x * blockDim.x + threadIdx.x;
  if (i >= NODES) return;
  int p = i >> PBITS, l = i & (PSIZE - 1);
  float2 z0 = z[i];
  float ax = z0.x, ay = z0.y;
#pragma unroll
  for (int s = 0; s < NSLICE; s++) {
    float2 v = hpart[(size_t)(p * NSLICE + s) * PSIZE + l];
    ax += v.x;
    ay += v.y;
  }
  float di = dinv[i];
  float l0 = di * ax + bias[0];
  float l1 = di * ay + bias[1];
  float m = fmaxf(l0, l1);
  float ls = m + logf(expf(l0 - m) + expf(l1 - m));
  float2 o;
  o.x = l0 - ls;
  o.y = l1 - ls;
  out[i] = o;
}

// ---------------------------------------------------------------------------
extern "C" void kernel_launch(void* const* d_in, const int* in_sizes, int n_in,
                              void* d_out, int out_size, void* d_ws,
                              size_t ws_size, hipStream_t stream) {
  const float* x = (const float*)d_in[0];
  const void* ei = d_in[1];
  const float* W = (const float*)d_in[2];
  const float* b = (const float*)d_in[3];
  float2* out = (float2*)d_out;

  char* w = (char*)d_ws;
  size_t off = 0;
  auto alloc = [&](size_t bytes) -> char* {
    char* p = w + off;
    off += (bytes + 255) & ~(size_t)255;
    return p;
  };
  int* mode = (int*)alloc(sizeof(int));
  int* cursor = (int*)alloc(P_BUCKETS * sizeof(int));
  int2* ecbuf = (int2*)alloc((size_t)P_BUCKETS * CAP * sizeof(int2));  // 26MB
  float* dinv = (float*)alloc(NODES * sizeof(float));
  float2* ts = (float2*)alloc(NODES * sizeof(float2));
  float2* z = (float2*)alloc(NODES * sizeof(float2));
  float2* hpart =
      (float2*)alloc((size_t)P_BUCKETS * NSLICE * PSIZE * sizeof(float2));
  (void)ws_size;

  const int NGRID = (NODES + 255) / 256;

  init_kernel<<<1, 64, 0, stream>>>(ei, mode, cursor);
  partition_kernel<<<PART_BLOCKS, 256, 0, stream>>>(ei, mode, cursor, ecbuf);
  deg_kernel<<<P_BUCKETS, 1024, 0, stream>>>(cursor, ecbuf, dinv);

  const int WPB = 256 / 64;  // 4 waves (nodes) per block
  proj_kernel<<<(NODES + WPB - 1) / WPB, 256, 0, stream>>>(x, W, dinv, ts);

  hop_kernel<<<P_BUCKETS * NSLICE, 512, 0, stream>>>(cursor, ecbuf, ts, hpart);
  merge1_kernel<<<NGRID, 256, 0, stream>>>(hpart, ts, dinv, z);
  hop_kernel<<<P_BUCKETS * NSLICE, 512, 0, stream>>>(cursor, ecbuf, z, hpart);
  merge2_kernel<<<NGRID, 256, 0, stream>>>(hpart, z, dinv, b, out);
}